// Round 4
// baseline (961.527 us; speedup 1.0000x reference)
//
#include <hip/hip_runtime.h>
#include <hip/hip_bf16.h>
#include <stdint.h>

// ---------------- types / helpers ----------------
typedef __attribute__((ext_vector_type(8))) short  short8;   // 8 bf16 (4 VGPR)
typedef __attribute__((ext_vector_type(4))) float  f32x4;
typedef __attribute__((ext_vector_type(4))) unsigned int uint4v;
typedef __attribute__((ext_vector_type(4))) unsigned short ushort4v;

#define MFMA16(a,b,c) __builtin_amdgcn_mfma_f32_16x16x32_bf16((a),(b),(c),0,0,0)

static __device__ __forceinline__ unsigned short f2bf(float x) {  // RNE, finite inputs
  unsigned int u = __float_as_uint(x);
  u += 0x7fffu + ((u >> 16) & 1u);
  return (unsigned short)(u >> 16);
}
static __device__ __forceinline__ float bf2f(unsigned short h) {
  return __uint_as_float(((unsigned int)h) << 16);
}

// problem constants
#define HDS   12
#define DD    128
#define DIMK  1536
#define NIN   4608      // 3*1536
#define LV    1920
#define LT    128
#define LL    2048
#define BB    2
#define MV    3840      // B*LV
#define MT    256       // B*LT
#define MTOT  4096

// ---------------- prep: split activations into bf16 hi/lo ----------------
__global__ __launch_bounds__(256) void split_x(const float* __restrict__ vid,
                                               const float* __restrict__ txt,
                                               unsigned short* __restrict__ xhi,
                                               unsigned short* __restrict__ xlo) {
  size_t i = ((size_t)blockIdx.x * 256 + threadIdx.x) * 4;
  const size_t NV = (size_t)MV * DIMK;
  const float* src = (i < NV) ? (vid + i) : (txt + (i - NV));
  f32x4 v = *(const f32x4*)src;
  ushort4v hv, lv;
#pragma unroll
  for (int j = 0; j < 4; ++j) {
    unsigned short h = f2bf(v[j]);
    hv[j] = h;
    lv[j] = f2bf(v[j] - bf2f(h));
  }
  *(ushort4v*)(xhi + i) = hv;
  *(ushort4v*)(xlo + i) = lv;
}

// ---------------- prep: W (K x N f32) -> W^T (N x K) bf16 hi/lo ----------------
__global__ __launch_bounds__(256) void transpose_split(const float* __restrict__ W,
                                                       unsigned short* __restrict__ Thi,
                                                       unsigned short* __restrict__ Tlo,
                                                       int K, int N) {
  __shared__ float tile[32][33];
  const int tx = threadIdx.x & 31, ty = threadIdx.x >> 5;  // 32 x 8
  const int k0 = blockIdx.y * 32, n0 = blockIdx.x * 32;
#pragma unroll
  for (int i = 0; i < 32; i += 8)
    tile[ty + i][tx] = W[(size_t)(k0 + ty + i) * N + n0 + tx];
  __syncthreads();
#pragma unroll
  for (int i = 0; i < 32; i += 8) {
    float v = tile[tx][ty + i];
    unsigned short h = f2bf(v);
    size_t o = (size_t)(n0 + ty + i) * K + k0 + tx;
    Thi[o] = h;
    Tlo[o] = f2bf(v - bf2f(h));
  }
}

// ---------------- prep: V (bh, L, D) -> Vt (bh, D, L) ----------------
__global__ __launch_bounds__(256) void vt_transpose(const unsigned short* __restrict__ v,
                                                    unsigned short* __restrict__ vtb) {
  __shared__ unsigned short tile[32][33];
  const int tx = threadIdx.x & 31, ty = threadIdx.x >> 5;
  const int bh = blockIdx.z;
  const int l0 = blockIdx.x * 32, d0 = blockIdx.y * 32;
  const size_t base = (size_t)bh * LL * DD;
#pragma unroll
  for (int i = 0; i < 32; i += 8)
    tile[ty + i][tx] = v[base + (size_t)(l0 + ty + i) * DD + d0 + tx];
  __syncthreads();
#pragma unroll
  for (int i = 0; i < 32; i += 8)
    vtb[base + (size_t)(d0 + ty + i) * LL + l0 + tx] = tile[tx][ty + i];
}

// ---------------- shared bf16x3 GEMM mainloop: 128x128 tile, K=1536, BK=32 ----------------
__device__ __forceinline__ void bf16x3_mainloop(
    const unsigned short* __restrict__ Ahi, const unsigned short* __restrict__ Alo,
    const unsigned short* __restrict__ Bhi, const unsigned short* __restrict__ Blo,
    int m0, int n0,
    uint4v* __restrict__ sAh, uint4v* __restrict__ sAl,
    uint4v* __restrict__ sBh, uint4v* __restrict__ sBl,
    f32x4 (&acc)[4][4]) {
  const int t = threadIdx.x;
  const int lane = t & 63;
  const int w = t >> 6;
  const int wm = w >> 1, wn = w & 1;
  const int lr = lane & 15, lg = lane >> 4;
  const int sr = t >> 1;          // staging row 0..127
  const int sc = (t & 1) * 2;     // staging chunk base (8 bf16 per chunk)
  const size_t arow = (size_t)(m0 + sr) * DIMK + sc * 8;
  const size_t brow = (size_t)(n0 + sr) * DIMK + sc * 8;
  const int slot0 = sc * 128 + sr, slot1 = (sc + 1) * 128 + sr;
  const int fA = lg * 128 + wm * 64 + lr;
  const int fB = lg * 128 + wn * 64 + lr;
  for (int k0 = 0; k0 < DIMK; k0 += 32) {
    uint4v va0 = *(const uint4v*)(Ahi + arow + k0);
    uint4v va1 = *(const uint4v*)(Ahi + arow + k0 + 8);
    uint4v va2 = *(const uint4v*)(Alo + arow + k0);
    uint4v va3 = *(const uint4v*)(Alo + arow + k0 + 8);
    uint4v vb0 = *(const uint4v*)(Bhi + brow + k0);
    uint4v vb1 = *(const uint4v*)(Bhi + brow + k0 + 8);
    uint4v vb2 = *(const uint4v*)(Blo + brow + k0);
    uint4v vb3 = *(const uint4v*)(Blo + brow + k0 + 8);
    __syncthreads();
    sAh[slot0] = va0; sAh[slot1] = va1;
    sAl[slot0] = va2; sAl[slot1] = va3;
    sBh[slot0] = vb0; sBh[slot1] = vb1;
    sBl[slot0] = vb2; sBl[slot1] = vb3;
    __syncthreads();
    short8 ah[4], al[4], bh[4], bl[4];
#pragma unroll
    for (int i = 0; i < 4; ++i) {
      ah[i] = *(const short8*)&sAh[fA + i * 16];
      al[i] = *(const short8*)&sAl[fA + i * 16];
      bh[i] = *(const short8*)&sBh[fB + i * 16];
      bl[i] = *(const short8*)&sBl[fB + i * 16];
    }
#pragma unroll
    for (int mi = 0; mi < 4; ++mi)
#pragma unroll
      for (int ni = 0; ni < 4; ++ni) {
        acc[mi][ni] = MFMA16(ah[mi], bh[ni], acc[mi][ni]);
        acc[mi][ni] = MFMA16(ah[mi], bl[ni], acc[mi][ni]);
        acc[mi][ni] = MFMA16(al[mi], bh[ni], acc[mi][ni]);
      }
  }
}

// ---------------- QKV GEMM + bias + RMSNorm(q,k) + pack to (B,H,L,D) bf16 ----------------
__global__ __launch_bounds__(256) void gemm_qkv(
    const unsigned short* __restrict__ Xhi, const unsigned short* __restrict__ Xlo,
    const unsigned short* __restrict__ WThi, const unsigned short* __restrict__ WTlo,
    const float* __restrict__ bias, const float* __restrict__ nqw, const float* __restrict__ nkw,
    unsigned short* __restrict__ qb, unsigned short* __restrict__ kb, unsigned short* __restrict__ vb,
    int Lmod, int loff) {
  __shared__ uint4v sAh[512], sAl[512], sBh[512], sBl[512];
  __shared__ float rowsq[2][128];
  const int t = threadIdx.x;
  const int lane = t & 63;
  const int w = t >> 6;
  const int wm = w >> 1, wn = w & 1;
  const int lr = lane & 15, lg = lane >> 4;
  const int m0 = blockIdx.y * 128, n0 = blockIdx.x * 128;
  f32x4 acc[4][4];
#pragma unroll
  for (int mi = 0; mi < 4; ++mi)
#pragma unroll
    for (int ni = 0; ni < 4; ++ni) acc[mi][ni] = (f32x4){0.f, 0.f, 0.f, 0.f};

  bf16x3_mainloop(Xhi, Xlo, WThi, WTlo, m0, n0, sAh, sAl, sBh, sBl, acc);

  const int s  = n0 / DIMK;              // 0=q 1=k 2=v
  const int hh = (n0 % DIMK) / DD;
#pragma unroll
  for (int ni = 0; ni < 4; ++ni) {
    float bv = bias[n0 + wn * 64 + ni * 16 + lr];
#pragma unroll
    for (int mi = 0; mi < 4; ++mi)
#pragma unroll
      for (int r = 0; r < 4; ++r) acc[mi][ni][r] += bv;
  }
  if (s < 2) {  // RMSNorm over the 128 cols of this tile (= head dim)
#pragma unroll
    for (int mi = 0; mi < 4; ++mi)
#pragma unroll
      for (int r = 0; r < 4; ++r) {
        float p = 0.f;
#pragma unroll
        for (int ni = 0; ni < 4; ++ni) p += acc[mi][ni][r] * acc[mi][ni][r];
        p += __shfl_xor(p, 1); p += __shfl_xor(p, 2);
        p += __shfl_xor(p, 4); p += __shfl_xor(p, 8);
        if (lr == 0) rowsq[wn][wm * 64 + mi * 16 + lg * 4 + r] = p;
      }
    __syncthreads();
    const float* nw = (s == 0) ? nqw : nkw;
    float nwv[4];
#pragma unroll
    for (int ni = 0; ni < 4; ++ni) nwv[ni] = nw[wn * 64 + ni * 16 + lr];
#pragma unroll
    for (int mi = 0; mi < 4; ++mi)
#pragma unroll
      for (int r = 0; r < 4; ++r) {
        int row = wm * 64 + mi * 16 + lg * 4 + r;
        float a = (rowsq[0][row] + rowsq[1][row]) * (1.f / 128.f) + 1e-6f;
        float x = rsqrtf(a);
        x = x * (1.5f - 0.5f * a * x * x);   // Newton refine -> ~f32 exact
#pragma unroll
        for (int ni = 0; ni < 4; ++ni) acc[mi][ni][r] *= x * nwv[ni];
      }
  }
  unsigned short* dst = (s == 0) ? qb : ((s == 1) ? kb : vb);
#pragma unroll
  for (int mi = 0; mi < 4; ++mi)
#pragma unroll
    for (int r = 0; r < 4; ++r) {
      int mrow = m0 + wm * 64 + mi * 16 + lg * 4 + r;
      int bidx = (mrow >= Lmod) ? 1 : 0;
      int l = loff + mrow - bidx * Lmod;
      size_t rb = ((size_t)(bidx * HDS + hh) * LL + l) * DD;
#pragma unroll
      for (int ni = 0; ni < 4; ++ni) {
        int d = wn * 64 + ni * 16 + lr;
        dst[rb + d] = f2bf(acc[mi][ni][r]);
      }
    }
}

// ---------------- attention v4: R1-proven skeleton (1 wave / 16 q-rows), ----------------
// latency-chain reduction: per-lane online (m,Z) in pass 1 (NO cross-lane ops
// in the loop), one 4-step butterfly merge after pass 1. QK accumulators split
// into two independent MFMA chains (depth 4 -> 2). Pass 2 identical to R1
// except the split accumulators.
__global__ __launch_bounds__(64) void attn_kernel(
    const unsigned short* __restrict__ qb, const unsigned short* __restrict__ kb,
    const unsigned short* __restrict__ vt,
    unsigned short* __restrict__ aohi, unsigned short* __restrict__ aolo) {
  const int lane = threadIdx.x;
  const int lr = lane & 15, lg = lane >> 4;
  const int bh = blockIdx.y, qt = blockIdx.x;
  const int q0 = qt * 16;
  const size_t base = (size_t)bh * LL * DD;
  const float scale = 0.08838834764831845f;  // 1/sqrt(128)
  __shared__ __align__(16) unsigned short P[16 * 40];  // padded: row stride 40 elems

  short8 qf[4];
#pragma unroll
  for (int ks = 0; ks < 4; ++ks)
    qf[ks] = *(const short8*)(qb + base + (size_t)(q0 + lr) * DD + ks * 32 + lg * 8);

  // per-lane online softmax state: lane covers cols {lr, 16+lr} of each tile,
  // rows lg*4+r. Exact-max online updates, merged across the row group later.
  float m[4], Z[4];
#pragma unroll
  for (int r = 0; r < 4; ++r) { m[r] = -1e30f; Z[r] = 0.f; }

  // ---- pass 1: per-lane max + sum (no cross-lane ops in loop) ----
  for (int kt = 0; kt < LL / 32; ++kt) {
    const int kv0 = kt * 32;
    f32x4 s0a = (f32x4){0.f, 0.f, 0.f, 0.f}, s0b = (f32x4){0.f, 0.f, 0.f, 0.f};
    f32x4 s1a = (f32x4){0.f, 0.f, 0.f, 0.f}, s1b = (f32x4){0.f, 0.f, 0.f, 0.f};
#pragma unroll
    for (int ks = 0; ks < 4; ++ks) {
      short8 k0f = *(const short8*)(kb + base + (size_t)(kv0 + lr) * DD + ks * 32 + lg * 8);
      short8 k1f = *(const short8*)(kb + base + (size_t)(kv0 + 16 + lr) * DD + ks * 32 + lg * 8);
      if (ks < 2) { s0a = MFMA16(qf[ks], k0f, s0a); s1a = MFMA16(qf[ks], k1f, s1a); }
      else        { s0b = MFMA16(qf[ks], k0f, s0b); s1b = MFMA16(qf[ks], k1f, s1b); }
    }
#pragma unroll
    for (int r = 0; r < 4; ++r) {
      float sa = (s0a[r] + s0b[r]) * scale;
      float sb = (s1a[r] + s1b[r]) * scale;
      float mx = fmaxf(sa, sb);
      float nm = fmaxf(m[r], mx);
      Z[r] = Z[r] * __expf(m[r] - nm) + (__expf(sa - nm) + __expf(sb - nm));
      m[r] = nm;
    }
  }
  // ---- merge (m,Z) across the 16-lane row group: 4-step butterfly ----
  float invZ[4];
#pragma unroll
  for (int r = 0; r < 4; ++r) {
#pragma unroll
    for (int mask = 1; mask <= 8; mask <<= 1) {
      float om = __shfl_xor(m[r], mask);
      float oZ = __shfl_xor(Z[r], mask);
      float nm = fmaxf(m[r], om);
      Z[r] = Z[r] * __expf(m[r] - nm) + oZ * __expf(om - nm);
      m[r] = nm;
    }
    invZ[r] = 1.0f / Z[r];
  }

  // ---- pass 2: probs = bf16(exp(s-m)/Z), PV ----
  f32x4 o[8];
#pragma unroll
  for (int i = 0; i < 8; ++i) o[i] = (f32x4){0.f, 0.f, 0.f, 0.f};
  for (int kt = 0; kt < LL / 32; ++kt) {
    const int kv0 = kt * 32;
    f32x4 s0a = (f32x4){0.f, 0.f, 0.f, 0.f}, s0b = (f32x4){0.f, 0.f, 0.f, 0.f};
    f32x4 s1a = (f32x4){0.f, 0.f, 0.f, 0.f}, s1b = (f32x4){0.f, 0.f, 0.f, 0.f};
#pragma unroll
    for (int ks = 0; ks < 4; ++ks) {
      short8 k0f = *(const short8*)(kb + base + (size_t)(kv0 + lr) * DD + ks * 32 + lg * 8);
      short8 k1f = *(const short8*)(kb + base + (size_t)(kv0 + 16 + lr) * DD + ks * 32 + lg * 8);
      if (ks < 2) { s0a = MFMA16(qf[ks], k0f, s0a); s1a = MFMA16(qf[ks], k1f, s1a); }
      else        { s0b = MFMA16(qf[ks], k0f, s0b); s1b = MFMA16(qf[ks], k1f, s1b); }
    }
#pragma unroll
    for (int r = 0; r < 4; ++r) {
      float p0 = __expf((s0a[r] + s0b[r]) * scale - m[r]) * invZ[r];
      float p1 = __expf((s1a[r] + s1b[r]) * scale - m[r]) * invZ[r];
      P[(lg * 4 + r) * 40 + lr]      = f2bf(p0);
      P[(lg * 4 + r) * 40 + 16 + lr] = f2bf(p1);
    }
    __syncthreads();
    short8 pa = *(const short8*)&P[lr * 40 + lg * 8];
#pragma unroll
    for (int df = 0; df < 8; ++df) {
      short8 vf = *(const short8*)(vt + base + (size_t)(df * 16 + lr) * LL + kv0 + lg * 8);
      o[df] = MFMA16(pa, vf, o[df]);
    }
    __syncthreads();
  }
  // write attention out as hi/lo bf16 in (outrow, H*D) layout
  const int b = bh / HDS, h = bh % HDS;
#pragma unroll
  for (int df = 0; df < 8; ++df)
#pragma unroll
    for (int r = 0; r < 4; ++r) {
      int l = q0 + lg * 4 + r;
      size_t row = (l < LV) ? ((size_t)b * LV + l) : ((size_t)MV + b * LT + (l - LV));
      int col = h * DD + df * 16 + lr;
      float val = o[df][r];
      unsigned short hi = f2bf(val);
      aohi[row * DIMK + col] = hi;
      aolo[row * DIMK + col] = f2bf(val - bf2f(hi));
    }
}

// ---------------- output GEMM + bias -> f32 d_out ----------------
__global__ __launch_bounds__(256) void gemm_out(
    const unsigned short* __restrict__ Ahi, const unsigned short* __restrict__ Alo,
    const unsigned short* __restrict__ WThi, const unsigned short* __restrict__ WTlo,
    const float* __restrict__ bias, float* __restrict__ out) {
  __shared__ uint4v sAh[512], sAl[512], sBh[512], sBl[512];
  const int t = threadIdx.x;
  const int lane = t & 63;
  const int w = t >> 6;
  const int wm = w >> 1, wn = w & 1;
  const int lr = lane & 15, lg = lane >> 4;
  const int m0 = blockIdx.y * 128, n0 = blockIdx.x * 128;
  f32x4 acc[4][4];
#pragma unroll
  for (int mi = 0; mi < 4; ++mi)
#pragma unroll
    for (int ni = 0; ni < 4; ++ni) acc[mi][ni] = (f32x4){0.f, 0.f, 0.f, 0.f};

  bf16x3_mainloop(Ahi, Alo, WThi, WTlo, m0, n0, sAh, sAl, sBh, sBl, acc);

#pragma unroll
  for (int ni = 0; ni < 4; ++ni) {
    float bv = bias[n0 + wn * 64 + ni * 16 + lr];
#pragma unroll
    for (int mi = 0; mi < 4; ++mi)
#pragma unroll
      for (int r = 0; r < 4; ++r) {
        size_t row = (size_t)(m0 + wm * 64 + mi * 16 + lg * 4 + r);
        out[row * DIMK + n0 + wn * 64 + ni * 16 + lr] = acc[mi][ni][r] + bv;
      }
  }
}

// ---------------- launcher ----------------
extern "C" void kernel_launch(void* const* d_in, const int* in_sizes, int n_in,
                              void* d_out, int out_size, void* d_ws, size_t ws_size,
                              hipStream_t stream) {
  (void)in_sizes; (void)n_in; (void)out_size; (void)ws_size;
  const float* vid      = (const float*)d_in[0];
  const float* txt      = (const float*)d_in[1];
  const float* Wqkv_vid = (const float*)d_in[2];
  const float* bqkv_vid = (const float*)d_in[3];
  const float* Wqkv_txt = (const float*)d_in[4];
  const float* bqkv_txt = (const float*)d_in[5];
  const float* nq_vid   = (const float*)d_in[6];
  const float* nk_vid   = (const float*)d_in[7];
  const float* nq_txt   = (const float*)d_in[8];
  const float* nk_txt   = (const float*)d_in[9];
  const float* Wout_vid = (const float*)d_in[10];
  const float* bout_vid = (const float*)d_in[11];
  const float* Wout_txt = (const float*)d_in[12];
  const float* bout_txt = (const float*)d_in[13];
  float* out = (float*)d_out;

  char* ws = (char*)d_ws;
  size_t off = 0;
  auto alloc = [&](size_t bytes) { char* p = ws + off; off += (bytes + 255) & ~(size_t)255; return p; };

  const size_t SZ_X    = (size_t)MTOT * DIMK * 2;   // bf16 bytes
  const size_t SZ_WQKV = (size_t)NIN * DIMK * 2;
  const size_t SZ_WOUT = (size_t)DIMK * DIMK * 2;
  const size_t SZ_QKVB = (size_t)BB * HDS * LL * DD * 2;

  unsigned short* Xhi   = (unsigned short*)alloc(SZ_X);
  unsigned short* Xlo   = (unsigned short*)alloc(SZ_X);
  unsigned short* WTqvH = (unsigned short*)alloc(SZ_WQKV);
  unsigned short* WTqvL = (unsigned short*)alloc(SZ_WQKV);
  unsigned short* WTqtH = (unsigned short*)alloc(SZ_WQKV);
  unsigned short* WTqtL = (unsigned short*)alloc(SZ_WQKV);
  unsigned short* WTovH = (unsigned short*)alloc(SZ_WOUT);
  unsigned short* WTovL = (unsigned short*)alloc(SZ_WOUT);
  unsigned short* WTotH = (unsigned short*)alloc(SZ_WOUT);
  unsigned short* WTotL = (unsigned short*)alloc(SZ_WOUT);
  unsigned short* QB    = (unsigned short*)alloc(SZ_QKVB);
  unsigned short* KB    = (unsigned short*)alloc(SZ_QKVB);
  unsigned short* VB    = (unsigned short*)alloc(SZ_QKVB);
  unsigned short* VT    = WTqvH;   // reuse: WTqv dead after QKV GEMMs
  unsigned short* AOhi  = Xhi;     // reuse: X dead after QKV GEMMs
  unsigned short* AOlo  = Xlo;

  split_x<<<dim3((MTOT * DIMK) / (256 * 4)), dim3(256), 0, stream>>>(vid, txt, Xhi, Xlo);
  transpose_split<<<dim3(NIN / 32, DIMK / 32), dim3(256), 0, stream>>>(Wqkv_vid, WTqvH, WTqvL, DIMK, NIN);
  transpose_split<<<dim3(NIN / 32, DIMK / 32), dim3(256), 0, stream>>>(Wqkv_txt, WTqtH, WTqtL, DIMK, NIN);
  transpose_split<<<dim3(DIMK / 32, DIMK / 32), dim3(256), 0, stream>>>(Wout_vid, WTovH, WTovL, DIMK, DIMK);
  transpose_split<<<dim3(DIMK / 32, DIMK / 32), dim3(256), 0, stream>>>(Wout_txt, WTotH, WTotL, DIMK, DIMK);
  gemm_qkv<<<dim3(NIN / 128, MV / 128), dim3(256), 0, stream>>>(
      Xhi, Xlo, WTqvH, WTqvL, bqkv_vid, nq_vid, nk_vid, QB, KB, VB, LV, 0);
  gemm_qkv<<<dim3(NIN / 128, MT / 128), dim3(256), 0, stream>>>(
      Xhi + (size_t)MV * DIMK, Xlo + (size_t)MV * DIMK, WTqtH, WTqtL, bqkv_txt, nq_txt, nk_txt,
      QB, KB, VB, LT, LV);
  vt_transpose<<<dim3(LL / 32, DD / 32, BB * HDS), dim3(256), 0, stream>>>(VB, VT);
  attn_kernel<<<dim3(LL / 16, BB * HDS), dim3(64), 0, stream>>>(QB, KB, VT, AOhi, AOlo);
  gemm_out<<<dim3(DIMK / 128, MV / 128), dim3(256), 0, stream>>>(
      AOhi, AOlo, WTovH, WTovL, bout_vid, out);
  gemm_out<<<dim3(DIMK / 128, MT / 128), dim3(256), 0, stream>>>(
      AOhi + (size_t)MV * DIMK, AOlo + (size_t)MV * DIMK, WTotH, WTotL, bout_txt,
      out + (size_t)MV * DIMK);
}

// Round 5
// 612.352 us; speedup vs baseline: 1.5702x; 1.5702x over previous
//
#include <hip/hip_runtime.h>
#include <hip/hip_bf16.h>
#include <stdint.h>

// ---------------- types / helpers ----------------
typedef __attribute__((ext_vector_type(8))) short  short8;   // 8 bf16 (4 VGPR)
typedef __attribute__((ext_vector_type(4))) float  f32x4;
typedef __attribute__((ext_vector_type(4))) unsigned int uint4v;
typedef __attribute__((ext_vector_type(4))) unsigned short ushort4v;

#define MFMA16(a,b,c) __builtin_amdgcn_mfma_f32_16x16x32_bf16((a),(b),(c),0,0,0)

#define AS1 __attribute__((address_space(1)))
#define AS3 __attribute__((address_space(3)))
static __device__ __forceinline__ void gload16(void* lds, const void* g) {
  // async global->LDS, 16B per lane; lds must be wave-uniform base, g is per-lane
  __builtin_amdgcn_global_load_lds((AS1 const void*)g, (AS3 void*)lds, 16, 0, 0);
}

static __device__ __forceinline__ unsigned short f2bf(float x) {  // RNE, finite inputs
  unsigned int u = __float_as_uint(x);
  u += 0x7fffu + ((u >> 16) & 1u);
  return (unsigned short)(u >> 16);
}
static __device__ __forceinline__ float bf2f(unsigned short h) {
  return __uint_as_float(((unsigned int)h) << 16);
}

// problem constants
#define HDS   12
#define DD    128
#define DIMK  1536
#define NIN   4608      // 3*1536
#define LV    1920
#define LT    128
#define LL    2048
#define BB    2
#define MV    3840      // B*LV
#define MT    256       // B*LT
#define MTOT  4096

// ---------------- prep: split activations into bf16 hi/lo ----------------
__global__ __launch_bounds__(256) void split_x(const float* __restrict__ vid,
                                               const float* __restrict__ txt,
                                               unsigned short* __restrict__ xhi,
                                               unsigned short* __restrict__ xlo) {
  size_t i = ((size_t)blockIdx.x * 256 + threadIdx.x) * 4;
  const size_t NV = (size_t)MV * DIMK;
  const float* src = (i < NV) ? (vid + i) : (txt + (i - NV));
  f32x4 v = *(const f32x4*)src;
  ushort4v hv, lv;
#pragma unroll
  for (int j = 0; j < 4; ++j) {
    unsigned short h = f2bf(v[j]);
    hv[j] = h;
    lv[j] = f2bf(v[j] - bf2f(h));
  }
  *(ushort4v*)(xhi + i) = hv;
  *(ushort4v*)(xlo + i) = lv;
}

// ---------------- prep: W (K x N f32) -> W^T (N x K) bf16 hi/lo ----------------
__global__ __launch_bounds__(256) void transpose_split(const float* __restrict__ W,
                                                       unsigned short* __restrict__ Thi,
                                                       unsigned short* __restrict__ Tlo,
                                                       int K, int N) {
  __shared__ float tile[32][33];
  const int tx = threadIdx.x & 31, ty = threadIdx.x >> 5;  // 32 x 8
  const int k0 = blockIdx.y * 32, n0 = blockIdx.x * 32;
#pragma unroll
  for (int i = 0; i < 32; i += 8)
    tile[ty + i][tx] = W[(size_t)(k0 + ty + i) * N + n0 + tx];
  __syncthreads();
#pragma unroll
  for (int i = 0; i < 32; i += 8) {
    float v = tile[tx][ty + i];
    unsigned short h = f2bf(v);
    size_t o = (size_t)(n0 + ty + i) * K + k0 + tx;
    Thi[o] = h;
    Tlo[o] = f2bf(v - bf2f(h));
  }
}

// ---------------- prep: V (bh, L, D) -> Vt (bh, D, L) ----------------
__global__ __launch_bounds__(256) void vt_transpose(const unsigned short* __restrict__ v,
                                                    unsigned short* __restrict__ vtb) {
  __shared__ unsigned short tile[32][33];
  const int tx = threadIdx.x & 31, ty = threadIdx.x >> 5;
  const int bh = blockIdx.z;
  const int l0 = blockIdx.x * 32, d0 = blockIdx.y * 32;
  const size_t base = (size_t)bh * LL * DD;
#pragma unroll
  for (int i = 0; i < 32; i += 8)
    tile[ty + i][tx] = v[base + (size_t)(l0 + ty + i) * DD + d0 + tx];
  __syncthreads();
#pragma unroll
  for (int i = 0; i < 32; i += 8)
    vtb[base + (size_t)(d0 + ty + i) * LL + l0 + tx] = tile[tx][ty + i];
}

// ---------------- shared bf16x3 GEMM mainloop: 128x128 tile, K=1536, BK=32 ----------------
__device__ __forceinline__ void bf16x3_mainloop(
    const unsigned short* __restrict__ Ahi, const unsigned short* __restrict__ Alo,
    const unsigned short* __restrict__ Bhi, const unsigned short* __restrict__ Blo,
    int m0, int n0,
    uint4v* __restrict__ sAh, uint4v* __restrict__ sAl,
    uint4v* __restrict__ sBh, uint4v* __restrict__ sBl,
    f32x4 (&acc)[4][4]) {
  const int t = threadIdx.x;
  const int lane = t & 63;
  const int w = t >> 6;
  const int wm = w >> 1, wn = w & 1;
  const int lr = lane & 15, lg = lane >> 4;
  const int sr = t >> 1;          // staging row 0..127
  const int sc = (t & 1) * 2;     // staging chunk base (8 bf16 per chunk)
  const size_t arow = (size_t)(m0 + sr) * DIMK + sc * 8;
  const size_t brow = (size_t)(n0 + sr) * DIMK + sc * 8;
  const int slot0 = sc * 128 + sr, slot1 = (sc + 1) * 128 + sr;
  const int fA = lg * 128 + wm * 64 + lr;
  const int fB = lg * 128 + wn * 64 + lr;
  for (int k0 = 0; k0 < DIMK; k0 += 32) {
    uint4v va0 = *(const uint4v*)(Ahi + arow + k0);
    uint4v va1 = *(const uint4v*)(Ahi + arow + k0 + 8);
    uint4v va2 = *(const uint4v*)(Alo + arow + k0);
    uint4v va3 = *(const uint4v*)(Alo + arow + k0 + 8);
    uint4v vb0 = *(const uint4v*)(Bhi + brow + k0);
    uint4v vb1 = *(const uint4v*)(Bhi + brow + k0 + 8);
    uint4v vb2 = *(const uint4v*)(Blo + brow + k0);
    uint4v vb3 = *(const uint4v*)(Blo + brow + k0 + 8);
    __syncthreads();
    sAh[slot0] = va0; sAh[slot1] = va1;
    sAl[slot0] = va2; sAl[slot1] = va3;
    sBh[slot0] = vb0; sBh[slot1] = vb1;
    sBl[slot0] = vb2; sBl[slot1] = vb3;
    __syncthreads();
    short8 ah[4], al[4], bh[4], bl[4];
#pragma unroll
    for (int i = 0; i < 4; ++i) {
      ah[i] = *(const short8*)&sAh[fA + i * 16];
      al[i] = *(const short8*)&sAl[fA + i * 16];
      bh[i] = *(const short8*)&sBh[fB + i * 16];
      bl[i] = *(const short8*)&sBl[fB + i * 16];
    }
#pragma unroll
    for (int mi = 0; mi < 4; ++mi)
#pragma unroll
      for (int ni = 0; ni < 4; ++ni) {
        acc[mi][ni] = MFMA16(ah[mi], bh[ni], acc[mi][ni]);
        acc[mi][ni] = MFMA16(ah[mi], bl[ni], acc[mi][ni]);
        acc[mi][ni] = MFMA16(al[mi], bh[ni], acc[mi][ni]);
      }
  }
}

// ---------------- QKV GEMM + bias + RMSNorm(q,k) + pack to (B,H,L,D) bf16 ----------------
__global__ __launch_bounds__(256) void gemm_qkv(
    const unsigned short* __restrict__ Xhi, const unsigned short* __restrict__ Xlo,
    const unsigned short* __restrict__ WThi, const unsigned short* __restrict__ WTlo,
    const float* __restrict__ bias, const float* __restrict__ nqw, const float* __restrict__ nkw,
    unsigned short* __restrict__ qb, unsigned short* __restrict__ kb, unsigned short* __restrict__ vb,
    int Lmod, int loff) {
  __shared__ uint4v sAh[512], sAl[512], sBh[512], sBl[512];
  __shared__ float rowsq[2][128];
  const int t = threadIdx.x;
  const int lane = t & 63;
  const int w = t >> 6;
  const int wm = w >> 1, wn = w & 1;
  const int lr = lane & 15, lg = lane >> 4;
  const int m0 = blockIdx.y * 128, n0 = blockIdx.x * 128;
  f32x4 acc[4][4];
#pragma unroll
  for (int mi = 0; mi < 4; ++mi)
#pragma unroll
    for (int ni = 0; ni < 4; ++ni) acc[mi][ni] = (f32x4){0.f, 0.f, 0.f, 0.f};

  bf16x3_mainloop(Xhi, Xlo, WThi, WTlo, m0, n0, sAh, sAl, sBh, sBl, acc);

  const int s  = n0 / DIMK;              // 0=q 1=k 2=v
  const int hh = (n0 % DIMK) / DD;
#pragma unroll
  for (int ni = 0; ni < 4; ++ni) {
    float bv = bias[n0 + wn * 64 + ni * 16 + lr];
#pragma unroll
    for (int mi = 0; mi < 4; ++mi)
#pragma unroll
      for (int r = 0; r < 4; ++r) acc[mi][ni][r] += bv;
  }
  if (s < 2) {  // RMSNorm over the 128 cols of this tile (= head dim)
#pragma unroll
    for (int mi = 0; mi < 4; ++mi)
#pragma unroll
      for (int r = 0; r < 4; ++r) {
        float p = 0.f;
#pragma unroll
        for (int ni = 0; ni < 4; ++ni) p += acc[mi][ni][r] * acc[mi][ni][r];
        p += __shfl_xor(p, 1); p += __shfl_xor(p, 2);
        p += __shfl_xor(p, 4); p += __shfl_xor(p, 8);
        if (lr == 0) rowsq[wn][wm * 64 + mi * 16 + lg * 4 + r] = p;
      }
    __syncthreads();
    const float* nw = (s == 0) ? nqw : nkw;
    float nwv[4];
#pragma unroll
    for (int ni = 0; ni < 4; ++ni) nwv[ni] = nw[wn * 64 + ni * 16 + lr];
#pragma unroll
    for (int mi = 0; mi < 4; ++mi)
#pragma unroll
      for (int r = 0; r < 4; ++r) {
        int row = wm * 64 + mi * 16 + lg * 4 + r;
        float a = (rowsq[0][row] + rowsq[1][row]) * (1.f / 128.f) + 1e-6f;
        float x = rsqrtf(a);
        x = x * (1.5f - 0.5f * a * x * x);   // Newton refine -> ~f32 exact
#pragma unroll
        for (int ni = 0; ni < 4; ++ni) acc[mi][ni][r] *= x * nwv[ni];
      }
  }
  unsigned short* dst = (s == 0) ? qb : ((s == 1) ? kb : vb);
#pragma unroll
  for (int mi = 0; mi < 4; ++mi)
#pragma unroll
    for (int r = 0; r < 4; ++r) {
      int mrow = m0 + wm * 64 + mi * 16 + lg * 4 + r;
      int bidx = (mrow >= Lmod) ? 1 : 0;
      int l = loff + mrow - bidx * Lmod;
      size_t rb = ((size_t)(bidx * HDS + hh) * LL + l) * DD;
#pragma unroll
      for (int ni = 0; ni < 4; ++ni) {
        int d = wn * 64 + ni * 16 + lr;
        dst[rb + d] = f2bf(acc[mi][ni][r]);
      }
    }
}

// ---------------- attention v5: 4 waves/block, each wave = independent q-tile ----------------
// Each wave runs the R4-proven per-wave algorithm verbatim (per-lane online m/Z,
// butterfly merge, exact 2-pass softmax). Waves share ONLY the double-buffered
// LDS staging of K and V tiles (global_load_lds, XOR-swizzled reads). No
// cross-wave numeric state whatsoever.
__global__ __launch_bounds__(256) void attn_kernel(
    const unsigned short* __restrict__ qb, const unsigned short* __restrict__ kb,
    const unsigned short* __restrict__ vt,
    unsigned short* __restrict__ aohi, unsigned short* __restrict__ aolo) {
  const int t = threadIdx.x;
  const int lane = t & 63, w = t >> 6;
  const int lr = lane & 15, lg = lane >> 4;
  const int bh = blockIdx.y;
  const int q0 = (blockIdx.x * 4 + w) * 16;
  const size_t base = (size_t)bh * LL * DD;
  const float scale = 0.08838834764831845f;  // 1/sqrt(128)

  __shared__ __align__(16) unsigned short Kbuf[2][32 * 128];  // [l-row][128 d], 8KB, swz (row&7)<<4
  __shared__ __align__(16) unsigned short Vbuf[2][128 * 32];  // [d-row][32 l], 8KB, swz (row&3)<<4
  __shared__ __align__(16) unsigned short P[4][16 * 40];      // per-wave, padded stride 40

  // ---- staging helpers: linear LDS dest, inverse-swizzled per-lane global src ----
  const char* kglob = (const char*)(kb + base);
  const char* vglob = (const char*)(vt + base);
  auto stageK = [&](int kt, int buf) {
    const char* gk = kglob + (size_t)kt * 32 * DD * 2;   // 8KB contiguous tile
#pragma unroll
    for (int is = 0; is < 2; ++is) {
      int Bl = is * 4096 + t * 16;                        // this lane's dest byte
      int Bu = is * 4096 + w * 1024;                      // wave-uniform dest base
      int src = Bl ^ (((Bl >> 8) & 7) << 4);              // involution within row
      gload16((char*)Kbuf[buf] + Bu, gk + src);
    }
  };
  auto stageV = [&](int kt, int buf) {
    const char* gv = vglob + kt * 64;                     // column offset kv0*2 bytes
#pragma unroll
    for (int is = 0; is < 2; ++is) {
      int Bl = is * 4096 + t * 16;
      int Bu = is * 4096 + w * 1024;
      int row = Bl >> 6;                                  // d index 0..127
      int ch  = ((Bl >> 4) & 3) ^ (row & 3);              // inverse swizzle
      gload16((char*)Vbuf[buf] + Bu, gv + (size_t)row * (LL * 2) + ch * 16);
    }
  };
  auto readK = [&](int buf, int rr, int ks) -> short8 {
    int byte = rr * 256 + ((ks * 64 + lg * 16) ^ ((rr & 7) << 4));
    return *(const short8*)((const char*)Kbuf[buf] + byte);
  };
  auto readV = [&](int buf, int df) -> short8 {
    int row = df * 16 + lr;
    int byte = row * 64 + ((lg ^ (row & 3)) << 4);
    return *(const short8*)((const char*)Vbuf[buf] + byte);
  };

  // ---- Q fragments (global, once) ----
  short8 qf[4];
#pragma unroll
  for (int ks = 0; ks < 4; ++ks)
    qf[ks] = *(const short8*)(qb + base + (size_t)(q0 + lr) * DD + ks * 32 + lg * 8);

  float m[4], Z[4];
#pragma unroll
  for (int r = 0; r < 4; ++r) { m[r] = -1e30f; Z[r] = 0.f; }

  // ---- pass 1: per-lane online max/sum over all 64 K tiles (K from LDS) ----
  stageK(0, 0);
  __syncthreads();
  for (int kt = 0; kt < LL / 32; ++kt) {
    const int cur = kt & 1;
    if (kt + 1 < LL / 32) stageK(kt + 1, cur ^ 1);
    f32x4 s0a = (f32x4){0.f, 0.f, 0.f, 0.f}, s0b = (f32x4){0.f, 0.f, 0.f, 0.f};
    f32x4 s1a = (f32x4){0.f, 0.f, 0.f, 0.f}, s1b = (f32x4){0.f, 0.f, 0.f, 0.f};
#pragma unroll
    for (int ks = 0; ks < 4; ++ks) {
      short8 k0f = readK(cur, lr, ks);
      short8 k1f = readK(cur, 16 + lr, ks);
      if (ks < 2) { s0a = MFMA16(qf[ks], k0f, s0a); s1a = MFMA16(qf[ks], k1f, s1a); }
      else        { s0b = MFMA16(qf[ks], k0f, s0b); s1b = MFMA16(qf[ks], k1f, s1b); }
    }
#pragma unroll
    for (int r = 0; r < 4; ++r) {
      float sa = (s0a[r] + s0b[r]) * scale;
      float sb = (s1a[r] + s1b[r]) * scale;
      float nm = fmaxf(m[r], fmaxf(sa, sb));
      Z[r] = Z[r] * __expf(m[r] - nm) + (__expf(sa - nm) + __expf(sb - nm));
      m[r] = nm;
    }
    __syncthreads();   // next tile staged (all waves' quarters) + everyone done with cur
  }
  // ---- merge (m,Z) across the 16-lane row group: 4-step butterfly ----
  float invZ[4];
#pragma unroll
  for (int r = 0; r < 4; ++r) {
#pragma unroll
    for (int mask = 1; mask <= 8; mask <<= 1) {
      float om = __shfl_xor(m[r], mask);
      float oZ = __shfl_xor(Z[r], mask);
      float nm = fmaxf(m[r], om);
      Z[r] = Z[r] * __expf(m[r] - nm) + oZ * __expf(om - nm);
      m[r] = nm;
    }
    invZ[r] = 1.0f / Z[r];
  }

  // ---- pass 2: probs = bf16(exp(s-m)/Z), PV (K,V from LDS) ----
  f32x4 o[8];
#pragma unroll
  for (int i = 0; i < 8; ++i) o[i] = (f32x4){0.f, 0.f, 0.f, 0.f};
  stageK(0, 0); stageV(0, 0);
  __syncthreads();
  for (int kt = 0; kt < LL / 32; ++kt) {
    const int cur = kt & 1;
    const int kv0 = kt * 32;
    if (kt + 1 < LL / 32) { stageK(kt + 1, cur ^ 1); stageV(kt + 1, cur ^ 1); }
    f32x4 s0a = (f32x4){0.f, 0.f, 0.f, 0.f}, s0b = (f32x4){0.f, 0.f, 0.f, 0.f};
    f32x4 s1a = (f32x4){0.f, 0.f, 0.f, 0.f}, s1b = (f32x4){0.f, 0.f, 0.f, 0.f};
#pragma unroll
    for (int ks = 0; ks < 4; ++ks) {
      short8 k0f = readK(cur, lr, ks);
      short8 k1f = readK(cur, 16 + lr, ks);
      if (ks < 2) { s0a = MFMA16(qf[ks], k0f, s0a); s1a = MFMA16(qf[ks], k1f, s1a); }
      else        { s0b = MFMA16(qf[ks], k0f, s0b); s1b = MFMA16(qf[ks], k1f, s1b); }
    }
    (void)kv0;
#pragma unroll
    for (int r = 0; r < 4; ++r) {
      float p0 = __expf((s0a[r] + s0b[r]) * scale - m[r]) * invZ[r];
      float p1 = __expf((s1a[r] + s1b[r]) * scale - m[r]) * invZ[r];
      P[w][(lg * 4 + r) * 40 + lr]      = f2bf(p0);
      P[w][(lg * 4 + r) * 40 + 16 + lr] = f2bf(p1);
    }
    __syncthreads();   // P visible (per-wave buffer, lockstep loop counts)
    short8 pa = *(const short8*)&P[w][lr * 40 + lg * 8];
#pragma unroll
    for (int df = 0; df < 8; ++df) {
      short8 vf = readV(cur, df);
      o[df] = MFMA16(pa, vf, o[df]);
    }
    __syncthreads();   // P WAR + staged tile complete before next iter
  }

  // ---- write attention out as hi/lo bf16 in (outrow, H*D) layout ----
  const int b = bh / HDS, h = bh % HDS;
#pragma unroll
  for (int df = 0; df < 8; ++df)
#pragma unroll
    for (int r = 0; r < 4; ++r) {
      int l = q0 + lg * 4 + r;
      size_t row = (l < LV) ? ((size_t)b * LV + l) : ((size_t)MV + b * LT + (l - LV));
      int col = h * DD + df * 16 + lr;
      float val = o[df][r];
      unsigned short hi = f2bf(val);
      aohi[row * DIMK + col] = hi;
      aolo[row * DIMK + col] = f2bf(val - bf2f(hi));
    }
}

// ---------------- output GEMM + bias -> f32 d_out ----------------
__global__ __launch_bounds__(256) void gemm_out(
    const unsigned short* __restrict__ Ahi, const unsigned short* __restrict__ Alo,
    const unsigned short* __restrict__ WThi, const unsigned short* __restrict__ WTlo,
    const float* __restrict__ bias, float* __restrict__ out) {
  __shared__ uint4v sAh[512], sAl[512], sBh[512], sBl[512];
  const int t = threadIdx.x;
  const int lane = t & 63;
  const int w = t >> 6;
  const int wm = w >> 1, wn = w & 1;
  const int lr = lane & 15, lg = lane >> 4;
  const int m0 = blockIdx.y * 128, n0 = blockIdx.x * 128;
  f32x4 acc[4][4];
#pragma unroll
  for (int mi = 0; mi < 4; ++mi)
#pragma unroll
    for (int ni = 0; ni < 4; ++ni) acc[mi][ni] = (f32x4){0.f, 0.f, 0.f, 0.f};

  bf16x3_mainloop(Ahi, Alo, WThi, WTlo, m0, n0, sAh, sAl, sBh, sBl, acc);

#pragma unroll
  for (int ni = 0; ni < 4; ++ni) {
    float bv = bias[n0 + wn * 64 + ni * 16 + lr];
#pragma unroll
    for (int mi = 0; mi < 4; ++mi)
#pragma unroll
      for (int r = 0; r < 4; ++r) {
        size_t row = (size_t)(m0 + wm * 64 + mi * 16 + lg * 4 + r);
        out[row * DIMK + n0 + wn * 64 + ni * 16 + lr] = acc[mi][ni][r] + bv;
      }
  }
}

// ---------------- launcher ----------------
extern "C" void kernel_launch(void* const* d_in, const int* in_sizes, int n_in,
                              void* d_out, int out_size, void* d_ws, size_t ws_size,
                              hipStream_t stream) {
  (void)in_sizes; (void)n_in; (void)out_size; (void)ws_size;
  const float* vid      = (const float*)d_in[0];
  const float* txt      = (const float*)d_in[1];
  const float* Wqkv_vid = (const float*)d_in[2];
  const float* bqkv_vid = (const float*)d_in[3];
  const float* Wqkv_txt = (const float*)d_in[4];
  const float* bqkv_txt = (const float*)d_in[5];
  const float* nq_vid   = (const float*)d_in[6];
  const float* nk_vid   = (const float*)d_in[7];
  const float* nq_txt   = (const float*)d_in[8];
  const float* nk_txt   = (const float*)d_in[9];
  const float* Wout_vid = (const float*)d_in[10];
  const float* bout_vid = (const float*)d_in[11];
  const float* Wout_txt = (const float*)d_in[12];
  const float* bout_txt = (const float*)d_in[13];
  float* out = (float*)d_out;

  char* ws = (char*)d_ws;
  size_t off = 0;
  auto alloc = [&](size_t bytes) { char* p = ws + off; off += (bytes + 255) & ~(size_t)255; return p; };

  const size_t SZ_X    = (size_t)MTOT * DIMK * 2;   // bf16 bytes
  const size_t SZ_WQKV = (size_t)NIN * DIMK * 2;
  const size_t SZ_WOUT = (size_t)DIMK * DIMK * 2;
  const size_t SZ_QKVB = (size_t)BB * HDS * LL * DD * 2;

  unsigned short* Xhi   = (unsigned short*)alloc(SZ_X);
  unsigned short* Xlo   = (unsigned short*)alloc(SZ_X);
  unsigned short* WTqvH = (unsigned short*)alloc(SZ_WQKV);
  unsigned short* WTqvL = (unsigned short*)alloc(SZ_WQKV);
  unsigned short* WTqtH = (unsigned short*)alloc(SZ_WQKV);
  unsigned short* WTqtL = (unsigned short*)alloc(SZ_WQKV);
  unsigned short* WTovH = (unsigned short*)alloc(SZ_WOUT);
  unsigned short* WTovL = (unsigned short*)alloc(SZ_WOUT);
  unsigned short* WTotH = (unsigned short*)alloc(SZ_WOUT);
  unsigned short* WTotL = (unsigned short*)alloc(SZ_WOUT);
  unsigned short* QB    = (unsigned short*)alloc(SZ_QKVB);
  unsigned short* KB    = (unsigned short*)alloc(SZ_QKVB);
  unsigned short* VB    = (unsigned short*)alloc(SZ_QKVB);
  unsigned short* VT    = WTqvH;   // reuse: WTqv dead after QKV GEMMs
  unsigned short* AOhi  = Xhi;     // reuse: X dead after QKV GEMMs
  unsigned short* AOlo  = Xlo;

  split_x<<<dim3((MTOT * DIMK) / (256 * 4)), dim3(256), 0, stream>>>(vid, txt, Xhi, Xlo);
  transpose_split<<<dim3(NIN / 32, DIMK / 32), dim3(256), 0, stream>>>(Wqkv_vid, WTqvH, WTqvL, DIMK, NIN);
  transpose_split<<<dim3(NIN / 32, DIMK / 32), dim3(256), 0, stream>>>(Wqkv_txt, WTqtH, WTqtL, DIMK, NIN);
  transpose_split<<<dim3(DIMK / 32, DIMK / 32), dim3(256), 0, stream>>>(Wout_vid, WTovH, WTovL, DIMK, DIMK);
  transpose_split<<<dim3(DIMK / 32, DIMK / 32), dim3(256), 0, stream>>>(Wout_txt, WTotH, WTotL, DIMK, DIMK);
  gemm_qkv<<<dim3(NIN / 128, MV / 128), dim3(256), 0, stream>>>(
      Xhi, Xlo, WTqvH, WTqvL, bqkv_vid, nq_vid, nk_vid, QB, KB, VB, LV, 0);
  gemm_qkv<<<dim3(NIN / 128, MT / 128), dim3(256), 0, stream>>>(
      Xhi + (size_t)MV * DIMK, Xlo + (size_t)MV * DIMK, WTqtH, WTqtL, bqkv_txt, nq_txt, nk_txt,
      QB, KB, VB, LT, LV);
  vt_transpose<<<dim3(LL / 32, DD / 32, BB * HDS), dim3(256), 0, stream>>>(VB, VT);
  attn_kernel<<<dim3(LL / 64, BB * HDS), dim3(256), 0, stream>>>(QB, KB, VT, AOhi, AOlo);
  gemm_out<<<dim3(DIMK / 128, MV / 128), dim3(256), 0, stream>>>(
      AOhi, AOlo, WTovH, WTovL, bout_vid, out);
  gemm_out<<<dim3(DIMK / 128, MT / 128), dim3(256), 0, stream>>>(
      AOhi + (size_t)MV * DIMK, AOlo + (size_t)MV * DIMK, WTotH, WTotL, bout_txt,
      out + (size_t)MV * DIMK);
}